// Round 2
// baseline (478.865 us; speedup 1.0000x reference)
//
#include <hip/hip_runtime.h>
#include <math.h>

#define F1 16
#define F2 8

typedef float f32x4 __attribute__((ext_vector_type(4)));

// Custom vectorized zero-fill for the 256 MB output.
// rocclr's fillBufferAligned measured 166 us; a grid-strided 16B non-temporal
// store stream should approach the ~6.3 TB/s write ceiling (~43 us for 268 MB).
__global__ void k_zero4(f32x4* __restrict__ p, long n4) {
    long i = (long)blockIdx.x * blockDim.x + threadIdx.x;
    long stride = (long)gridDim.x * blockDim.x;
    f32x4 z = {0.0f, 0.0f, 0.0f, 0.0f};
    for (; i < n4; i += stride) {
        __builtin_nontemporal_store(z, &p[i]);
    }
}

// Fused: scatter 1.0 at every directed edge position of out AND count in-degree.
__global__ void k_edges0(const int* __restrict__ src, const int* __restrict__ dst,
                         float* __restrict__ out, float* __restrict__ deg,
                         int E, int N) {
    int e = blockIdx.x * blockDim.x + threadIdx.x;
    if (e < E) {
        int s = src[e], d = dst[e];
        out[(long)s * N + d] = 1.0f;
        atomicAdd(&deg[d], 1.0f);
    }
}

// conv1 aggregation: x1[dst] += norm * W1[src]; norm computed inline from deg.
// (x1 pre-zeroed by memset; deg holds in-degree counts, +1 for self-loop)
__global__ void k_conv1_edges(const int* __restrict__ src, const int* __restrict__ dst,
                              const float* __restrict__ deg, const float* __restrict__ W1,
                              float* __restrict__ x1, int E) {
    int id = blockIdx.x * blockDim.x + threadIdx.x;
    int e = id >> 4;
    int f = id & (F1 - 1);
    if (e < E) {
        int s = src[e], d = dst[e];
        float nrm = rsqrtf((deg[s] + 1.0f) * (deg[d] + 1.0f));
        atomicAdd(&x1[(long)d * F1 + f], nrm * W1[(long)s * F1 + f]);
    }
}

// Per (node, out-feature): r = relu(x1 + W1/(deg+1) + b1); h2[i,g] = sum_f r[f]*W2[f,g]
__global__ void k_layer1(const float* __restrict__ deg, const float* __restrict__ b1,
                         const float* __restrict__ W1, const float* __restrict__ W2,
                         const float* __restrict__ x1, float* __restrict__ h2, int N) {
    int id = blockIdx.x * blockDim.x + threadIdx.x;
    if (id < N * F2) {
        int i = id >> 3;        // node
        int g = id & (F2 - 1);  // out feature
        float sw = 1.0f / (deg[i] + 1.0f);
        float acc = 0.0f;
        #pragma unroll
        for (int f = 0; f < F1; ++f) {
            float v = x1[(long)i * F1 + f] + sw * W1[(long)i * F1 + f] + b1[f];
            v = v > 0.0f ? v : 0.0f;
            acc += v * W2[f * F2 + g];
        }
        h2[(long)i * F2 + g] = acc;
    }
}

// conv2 aggregation: x2[dst] += norm * h2[src]; norm inline from deg.
__global__ void k_conv2_edges(const int* __restrict__ src, const int* __restrict__ dst,
                              const float* __restrict__ deg, const float* __restrict__ h2,
                              float* __restrict__ x2, int E) {
    int id = blockIdx.x * blockDim.x + threadIdx.x;
    int e = id >> 3;
    int g = id & (F2 - 1);
    if (e < E) {
        int s = src[e], d = dst[e];
        float nrm = rsqrtf((deg[s] + 1.0f) * (deg[d] + 1.0f));
        atomicAdd(&x2[(long)d * F2 + g], nrm * h2[(long)s * F2 + g]);
    }
}

// Per undirected edge: finish conv2 (self term + bias + relu) inline, score, scatter.
__global__ void k_orient(const int2* __restrict__ ue, const float* __restrict__ x2,
                         const float* __restrict__ h2, const float* __restrict__ deg,
                         const float* __restrict__ b2, const float* __restrict__ Wfc,
                         const float* __restrict__ bfc, float* __restrict__ out,
                         int U, int N) {
    int k = blockIdx.x * blockDim.x + threadIdx.x;
    if (k < U) {
        int2 e = ue[k];
        int u = e.x, v = e.y;
        float swu = 1.0f / (deg[u] + 1.0f);
        float swv = 1.0f / (deg[v] + 1.0f);
        float s = bfc[0];
        #pragma unroll
        for (int g = 0; g < F2; ++g) {
            float xu = x2[(long)u * F2 + g] + swu * h2[(long)u * F2 + g] + b2[g];
            float xv = x2[(long)v * F2 + g] + swv * h2[(long)v * F2 + g] + b2[g];
            xu = xu > 0.0f ? xu : 0.0f;
            xv = xv > 0.0f ? xv : 0.0f;
            s += xu * Wfc[g] + xv * Wfc[F2 + g];
        }
        float orient = 1.0f / (1.0f + expf(-s));
        out[(long)u * N + v] = orient;
        out[(long)v * N + u] = 1.0f - orient;
    }
}

extern "C" void kernel_launch(void* const* d_in, const int* in_sizes, int n_in,
                              void* d_out, int out_size, void* d_ws, size_t ws_size,
                              hipStream_t stream) {
    const float* W1  = (const float*)d_in[1];
    const float* b1  = (const float*)d_in[2];
    const float* W2  = (const float*)d_in[3];
    const float* b2  = (const float*)d_in[4];
    const float* Wfc = (const float*)d_in[5];
    const float* bfc = (const float*)d_in[6];
    const int* edge_index = (const int*)d_in[7];
    const int2* und       = (const int2*)d_in[8];

    int N = in_sizes[1] / F1;      // 8192
    int E = in_sizes[7] / 2;
    int U = in_sizes[8] / 2;
    const int* src = edge_index;
    const int* dst = edge_index + E;

    // ws layout: [deg(N) | x1(16N) | x2(8N)] (zeroed) | h2(8N) (written before read)
    float* ws  = (float*)d_ws;
    float* deg = ws;
    float* x1  = ws + N;
    float* x2  = x1 + (long)F1 * N;
    float* h2  = x2 + (long)F2 * N;

    const int B = 256;

    // Zero output with our own 16B streaming-store kernel (replaces
    // hipMemsetAsync / rocclr fillBufferAligned which measured 166 us).
    {
        long n4 = ((long)N * N) / 4;
        int blocks = 2048;   // 2048*256 threads = 32 waves/CU on 256 CUs
        k_zero4<<<blocks, B, 0, stream>>>((f32x4*)d_out, n4);
    }
    // Zero deg + x1 + x2 in one contiguous memset (800 KB, cheap).
    (void)hipMemsetAsync(d_ws, 0, (size_t)(N + (long)F1 * N + (long)F2 * N) * sizeof(float), stream);

    // ones-scatter + degree count (fused)
    k_edges0<<<(E + B - 1) / B, B, 0, stream>>>(src, dst, (float*)d_out, deg, E, N);

    // conv1 aggregation (norm inline)
    {
        long work = (long)E * F1;
        k_conv1_edges<<<(int)((work + B - 1) / B), B, 0, stream>>>(src, dst, deg, W1, x1, E);
    }
    // layer1: relu + 16x8 matmul, (node, feature)-parallel
    k_layer1<<<(N * F2 + B - 1) / B, B, 0, stream>>>(deg, b1, W1, W2, x1, h2, N);

    // conv2 aggregation (norm inline)
    {
        long work = (long)E * F2;
        k_conv2_edges<<<(int)((work + B - 1) / B), B, 0, stream>>>(src, dst, deg, h2, x2, E);
    }

    // orient scoring + scatter (conv2 self term + bias + relu inline)
    k_orient<<<(U + B - 1) / B, B, 0, stream>>>(und, x2, h2, deg, b2, Wfc, bfc,
                                                (float*)d_out, U, N);
}